// Round 1
// baseline (77.793 us; speedup 1.0000x reference)
//
#include <hip/hip_runtime.h>
#include <math.h>

#define BATCH 32
#define CH    256
#define HH    64
#define WW    64
#define HW    (HH * WW)          // 4096
#define NPIX  (BATCH * HW)       // 131072
#define NTOT  ((size_t)BATCH * CH * HW)  // 33554432

// Kernel 1: channel-wise mean + max -> pooled [B, H, W]
__global__ __launch_bounds__(256) void sa_pool_kernel(
    const float* __restrict__ x, float* __restrict__ pooled) {
    int idx = blockIdx.x * blockDim.x + threadIdx.x;
    if (idx >= NPIX) return;
    int b  = idx >> 12;          // / 4096
    int hw = idx & 4095;
    const float* p = x + (size_t)b * CH * HW + hw;
    float s = 0.0f;
    float m = -INFINITY;
#pragma unroll 8
    for (int c = 0; c < CH; ++c) {
        float v = p[(size_t)c * HW];
        s += v;
        m = fmaxf(m, v);
    }
    pooled[idx] = s * (1.0f / (float)CH) + m;
}

// Kernel 2: 7x7 SAME conv (1->1 ch) + bias + sigmoid -> attn [B, H, W]
__global__ __launch_bounds__(256) void sa_conv_kernel(
    const float* __restrict__ pooled, const float* __restrict__ wgt,
    const float* __restrict__ bias, float* __restrict__ attn) {
    int idx = blockIdx.x * blockDim.x + threadIdx.x;
    if (idx >= NPIX) return;
    int b  = idx >> 12;
    int hw = idx & 4095;
    int h  = hw >> 6;
    int w  = hw & 63;
    const float* pb = pooled + b * HW;
    float acc = bias[0];
#pragma unroll
    for (int kh = 0; kh < 7; ++kh) {
        int hh2 = h + kh - 3;
        if (hh2 < 0 || hh2 >= HH) continue;
#pragma unroll
        for (int kw = 0; kw < 7; ++kw) {
            int ww2 = w + kw - 3;
            if (ww2 < 0 || ww2 >= WW) continue;
            acc += pb[hh2 * WW + ww2] * wgt[kh * 7 + kw];
        }
    }
    attn[idx] = 1.0f / (1.0f + __expf(-acc));
}

// Kernel 3: out = x * attn (broadcast over channels), float4 vectorized
__global__ __launch_bounds__(256) void sa_mul_kernel(
    const float* __restrict__ x, const float* __restrict__ attn,
    float* __restrict__ out) {
    size_t i = ((size_t)blockIdx.x * blockDim.x + threadIdx.x) * 4;
    if (i >= NTOT) return;
    size_t bc = i >> 12;         // b*CH + c
    int hw    = (int)(i & 4095);
    int b     = (int)(bc >> 8);  // / 256
    float4 xv = *reinterpret_cast<const float4*>(x + i);
    float4 av = *reinterpret_cast<const float4*>(attn + (size_t)b * HW + hw);
    float4 o;
    o.x = xv.x * av.x;
    o.y = xv.y * av.y;
    o.z = xv.z * av.z;
    o.w = xv.w * av.w;
    *reinterpret_cast<float4*>(out + i) = o;
}

extern "C" void kernel_launch(void* const* d_in, const int* in_sizes, int n_in,
                              void* d_out, int out_size, void* d_ws, size_t ws_size,
                              hipStream_t stream) {
    const float* x    = (const float*)d_in[0];
    const float* wgt  = (const float*)d_in[1];
    const float* bias = (const float*)d_in[2];
    float* out = (float*)d_out;

    // scratch layout: pooled [NPIX] floats, attn [NPIX] floats
    float* pooled = (float*)d_ws;
    float* attn   = pooled + NPIX;

    {
        dim3 block(256);
        dim3 grid((NPIX + 255) / 256);   // 512 blocks
        sa_pool_kernel<<<grid, block, 0, stream>>>(x, pooled);
    }
    {
        dim3 block(256);
        dim3 grid((NPIX + 255) / 256);   // 512 blocks
        sa_conv_kernel<<<grid, block, 0, stream>>>(pooled, wgt, bias, attn);
    }
    {
        dim3 block(256);
        dim3 grid((unsigned)((NTOT / 4 + 255) / 256));  // 32768 blocks
        sa_mul_kernel<<<grid, block, 0, stream>>>(x, attn, out);
    }
}